// Round 7
// baseline (407.785 us; speedup 1.0000x reference)
//
#include <hip/hip_runtime.h>
#include <hip/hip_bf16.h>
#include <math.h>

#define NIN 128
#define HC 128
#define NOUT 768

typedef __attribute__((ext_vector_type(8))) short bf16x8;
typedef __attribute__((ext_vector_type(4))) float f32x4;
typedef __attribute__((ext_vector_type(4))) unsigned short ushort4v;
typedef __attribute__((ext_vector_type(8))) unsigned short ushort8v;

__device__ __forceinline__ unsigned short f2bf(float f) {
    __hip_bfloat16 h = __float2bfloat16(f);
    return *(unsigned short*)&h;
}

// ---------------- prep: W[k][n] fp32 -> Wt[n][k] bf16 (4 weights) ----------------
__global__ __launch_bounds__(256) void prep_w(
    const float* __restrict__ Wq, const float* __restrict__ Wk,
    const float* __restrict__ Wv, const float* __restrict__ Wsk,
    unsigned short* __restrict__ Wtb)
{
    const float* W = (blockIdx.x == 0) ? Wq : (blockIdx.x == 1) ? Wk
                   : (blockIdx.x == 2) ? Wv : Wsk;
    unsigned short* out = Wtb + (size_t)blockIdx.x * 128 * 128;
    const int t = threadIdx.x;
    for (int s = 0; s < 16; ++s) {
        const int f = t + s * 256;           // float4 index (4096 total)
        const int k = f >> 5;
        const int n = (f & 31) * 4;
        float4 w4 = *(const float4*)(W + (size_t)k * 128 + n);
        out[(size_t)(n    ) * 128 + k] = f2bf(w4.x);
        out[(size_t)(n + 1) * 128 + k] = f2bf(w4.y);
        out[(size_t)(n + 2) * 128 + k] = f2bf(w4.z);
        out[(size_t)(n + 3) * 128 + k] = f2bf(w4.w);
    }
}

// ---------------- Kernel A: MFMA projections, LDS-free ----------------
// 64 rows per block, 4 waves x 16 rows, all 4 weights per block.
// A-fragments loaded straight from x (each wave covers full 128B lines of its
// 16 rows); swapped-operand MFMA so each lane owns 4 consecutive out columns.
// No LDS, no barriers -> pure streaming, TLP hides latency.
__global__ __launch_bounds__(256, 6) void gemm4_mfma(
    const float* __restrict__ x, const unsigned short* __restrict__ Wtb,
    const float* __restrict__ bq, const float* __restrict__ bk,
    const float* __restrict__ bv, const float* __restrict__ bsk,
    __hip_bfloat16* __restrict__ outbase, int N)
{
    const int tid = threadIdx.x;
    const int lane = tid & 63;
    const int wave = tid >> 6;
    const int row = blockIdx.x * 64 + wave * 16 + (lane & 15);
    const bool rowok = row < N;
    const int kofs = (lane >> 4) * 8;       // float offset within the 32-float k-slab
    const int g4   = (lane >> 4) * 4;

    // A fragments (used as the MFMA *B* operand): row = lane&15 within wave tile
    bf16x8 afr[4];
    #pragma unroll
    for (int kk = 0; kk < 4; ++kk) {
        float4 a0 = make_float4(0.f, 0.f, 0.f, 0.f), a1 = a0;
        if (rowok) {
            const float* xp = x + (size_t)row * 128 + kk * 32 + kofs;
            a0 = *(const float4*)xp;
            a1 = *(const float4*)(xp + 4);
        }
        union { unsigned short h[8]; bf16x8 v; } u;
        u.h[0] = f2bf(a0.x); u.h[1] = f2bf(a0.y); u.h[2] = f2bf(a0.z); u.h[3] = f2bf(a0.w);
        u.h[4] = f2bf(a1.x); u.h[5] = f2bf(a1.y); u.h[6] = f2bf(a1.z); u.h[7] = f2bf(a1.w);
        afr[kk] = u.v;
    }

    const int colb = lane & 15;

    for (int w = 0; w < 4; ++w) {
        const unsigned short* Wp = Wtb + (size_t)w * 128 * 128;
        const float* bias = (w == 0) ? bq : (w == 1) ? bk : (w == 2) ? bv : bsk;
        __hip_bfloat16* out = outbase + (size_t)w * (size_t)N * 128;

        f32x4 acc[8];
        #pragma unroll
        for (int nr = 0; nr < 8; ++nr)
            acc[nr] = (f32x4){0.f, 0.f, 0.f, 0.f};

        #pragma unroll
        for (int nr = 0; nr < 8; ++nr) {
            bf16x8 bfr[4];
            #pragma unroll
            for (int kk = 0; kk < 4; ++kk)
                bfr[kk] = *(const bf16x8*)(Wp + (size_t)(nr * 16 + colb) * 128
                                               + kk * 32 + kofs);
            #pragma unroll
            for (int kk = 0; kk < 4; ++kk)
                acc[nr] = __builtin_amdgcn_mfma_f32_16x16x32_bf16(
                    bfr[kk], afr[kk], acc[nr], 0, 0, 0);   // swapped operands
        }

        // store: lane holds out[row][nr*16 + g4 + j], j=0..3
        if (rowok) {
            #pragma unroll
            for (int nr = 0; nr < 8; ++nr) {
                const int colb4 = nr * 16 + g4;
                const float4 b4 = *(const float4*)(bias + colb4);
                ushort4v pk;
                pk.x = f2bf(acc[nr][0] + b4.x);
                pk.y = f2bf(acc[nr][1] + b4.y);
                pk.z = f2bf(acc[nr][2] + b4.z);
                pk.w = f2bf(acc[nr][3] + b4.w);
                *(ushort4v*)(out + (size_t)row * 128 + colb4) = pk;
            }
        }
    }
}

// ---------------- CSR build ----------------
__global__ __launch_bounds__(256) void hist_kernel(
    const int* __restrict__ ei, int* __restrict__ cnt, int E)
{
    const int e = blockIdx.x * 256 + threadIdx.x;
    if (e < E) atomicAdd(cnt + ei[E + e], 1);
}

__global__ __launch_bounds__(1024) void scan_part(
    const int* __restrict__ cnt, int* __restrict__ start,
    int* __restrict__ bsum, int N)
{
    __shared__ int wsum[16];
    const int tid = threadIdx.x;
    const int lane = tid & 63;
    const int w = tid >> 6;
    const int i = blockIdx.x * 1024 + tid;
    const int v = (i < N) ? cnt[i] : 0;
    int xv = v;
    #pragma unroll
    for (int off = 1; off < 64; off <<= 1) {
        const int y = __shfl_up(xv, off, 64);
        if (lane >= off) xv += y;
    }
    if (lane == 63) wsum[w] = xv;
    __syncthreads();
    if (tid < 16) {
        int y = wsum[tid];
        #pragma unroll
        for (int off = 1; off < 16; off <<= 1) {
            const int z = __shfl_up(y, off, 64);
            if (tid >= off) y += z;
        }
        wsum[tid] = y;
    }
    __syncthreads();
    const int excl = (w > 0 ? wsum[w - 1] : 0) + xv - v;
    if (i < N) start[i] = excl;
    if (tid == 1023) bsum[blockIdx.x] = wsum[15];
}

__global__ __launch_bounds__(128) void scan_bsum(int* __restrict__ bsum, int NB)
{
    const int tid = threadIdx.x;
    __shared__ int w0tot;
    const int v = (tid < NB) ? bsum[tid] : 0;
    int xv = v;
    const int lane = tid & 63;
    #pragma unroll
    for (int off = 1; off < 64; off <<= 1) {
        const int y = __shfl_up(xv, off, 64);
        if (lane >= off) xv += y;
    }
    if (tid == 63) w0tot = xv;
    __syncthreads();
    const int incl = xv + ((tid >= 64) ? w0tot : 0);
    if (tid < NB) bsum[tid] = incl - v;     // exclusive
}

__global__ __launch_bounds__(256) void scan_add(
    int* __restrict__ start, int* __restrict__ cursor,
    const int* __restrict__ bsum, int N)
{
    const int i = blockIdx.x * 256 + threadIdx.x;
    if (i < N) {
        const int s = start[i] + bsum[i >> 10];
        start[i] = s;
        cursor[i] = s;
    }
}

__global__ __launch_bounds__(256) void scatter_kernel(
    const int* __restrict__ ei, int* __restrict__ cursor,
    int* __restrict__ csr_src, int E)
{
    const int e = blockIdx.x * 256 + threadIdx.x;
    if (e < E) {
        const int d = ei[E + e];
        const int pos = atomicAdd(cursor + d, 1);
        csr_src[pos] = ei[e];
    }
}

// ---------------- Kernel B: node-centric attention + gate (no atomics) ----------------
__global__ __launch_bounds__(256) void node_aggr(
    const __hip_bfloat16* __restrict__ q, const __hip_bfloat16* __restrict__ k,
    const __hip_bfloat16* __restrict__ v, const __hip_bfloat16* __restrict__ skip,
    const int* __restrict__ start, const int* __restrict__ cnt,
    const int* __restrict__ csr_src, const float* __restrict__ Wbeta,
    __hip_bfloat16* __restrict__ gout, int N)
{
    const int n = blockIdx.x * 4 + (threadIdx.x >> 6);
    if (n >= N) return;
    const int lane = threadIdx.x & 63;
    const int c = 2 * lane;
    const float scale = 0.17677669529663687f;   // 1/sqrt(32)

    const __hip_bfloat162 q2 = *(const __hip_bfloat162*)(q + (size_t)n * HC + c);
    const float qx = __bfloat162float(q2.x), qy = __bfloat162float(q2.y);

    const int s0 = start[n];
    const int e1 = s0 + cnt[n];
    float den = 0.f, a0 = 0.f, a1 = 0.f;
    int i = s0;
    for (; i + 1 < e1; i += 2) {
        const int sa = csr_src[i];
        const int sb = csr_src[i + 1];
        const __hip_bfloat162 k2a = *(const __hip_bfloat162*)(k + (size_t)sa * HC + c);
        const __hip_bfloat162 v2a = *(const __hip_bfloat162*)(v + (size_t)sa * HC + c);
        const __hip_bfloat162 k2b = *(const __hip_bfloat162*)(k + (size_t)sb * HC + c);
        const __hip_bfloat162 v2b = *(const __hip_bfloat162*)(v + (size_t)sb * HC + c);
        float pa = qx * __bfloat162float(k2a.x) + qy * __bfloat162float(k2a.y);
        float pb = qx * __bfloat162float(k2b.x) + qy * __bfloat162float(k2b.y);
        #pragma unroll
        for (int m = 1; m < 16; m <<= 1) {
            pa += __shfl_xor(pa, m, 64);
            pb += __shfl_xor(pb, m, 64);
        }
        const float exa = __expf(pa * scale);
        const float exb = __expf(pb * scale);
        den += exa + exb;
        a0 = fmaf(__bfloat162float(v2a.x), exa, fmaf(__bfloat162float(v2b.x), exb, a0));
        a1 = fmaf(__bfloat162float(v2a.y), exa, fmaf(__bfloat162float(v2b.y), exb, a1));
    }
    if (i < e1) {
        const int sa = csr_src[i];
        const __hip_bfloat162 k2a = *(const __hip_bfloat162*)(k + (size_t)sa * HC + c);
        const __hip_bfloat162 v2a = *(const __hip_bfloat162*)(v + (size_t)sa * HC + c);
        float pa = qx * __bfloat162float(k2a.x) + qy * __bfloat162float(k2a.y);
        #pragma unroll
        for (int m = 1; m < 16; m <<= 1) pa += __shfl_xor(pa, m, 64);
        const float exa = __expf(pa * scale);
        den += exa;
        a0 = fmaf(__bfloat162float(v2a.x), exa, a0);
        a1 = fmaf(__bfloat162float(v2a.y), exa, a1);
    }

    const float inv = 1.f / (den + 1e-16f);
    const float o0 = a0 * inv, o1 = a1 * inv;

    const __hip_bfloat162 s2 = *(const __hip_bfloat162*)(skip + (size_t)n * HC + c);
    const float sk0 = __bfloat162float(s2.x);
    const float sk1 = __bfloat162float(s2.y);

    float part = o0 * Wbeta[c]     + sk0 * Wbeta[HC + c]     + (o0 - sk0) * Wbeta[2 * HC + c]
               + o1 * Wbeta[c + 1] + sk1 * Wbeta[HC + c + 1] + (o1 - sk1) * Wbeta[2 * HC + c + 1];
    #pragma unroll
    for (int m = 1; m < 64; m <<= 1) part += __shfl_xor(part, m, 64);

    const float beta = 1.f / (1.f + __expf(-part));
    float r0 = beta * sk0 + (1.f - beta) * o0;
    float r1 = beta * sk1 + (1.f - beta) * o1;
    r0 = (r0 >= 0.f) ? r0 : 0.01f * r0;
    r1 = (r1 >= 0.f) ? r1 : 0.01f * r1;

    __hip_bfloat162 g2;
    g2.x = __float2bfloat16(r0);
    g2.y = __float2bfloat16(r1);
    *(__hip_bfloat162*)(gout + (size_t)n * HC + c) = g2;
}

// ---------------- pool per graph (batch sorted; binary search the range) ----------------
__global__ __launch_bounds__(128) void pool_graph(
    const __hip_bfloat16* __restrict__ gout, const int* __restrict__ batch,
    float* __restrict__ pooled, int N)
{
    const int g = blockIdx.x;
    const int t = threadIdx.x;
    int lo = 0, hi = N;
    while (lo < hi) { const int m = (lo + hi) >> 1; if (batch[m] < g) lo = m + 1; else hi = m; }
    int lo2 = lo, hi2 = N;
    while (lo2 < hi2) { const int m = (lo2 + hi2) >> 1; if (batch[m] < g + 1) lo2 = m + 1; else hi2 = m; }
    float acc = 0.f;
    for (int r = lo; r < lo2; ++r)
        acc += __bfloat162float(gout[(size_t)r * HC + t]);
    pooled[(size_t)g * HC + t] = acc / fmaxf((float)(lo2 - lo), 1.f);
}

// ---------------- final GEMM: 4 graphs per block (W2 reuse x4) ----------------
__global__ __launch_bounds__(256) void final_gemm(
    const float* __restrict__ pooled,
    const float* __restrict__ W2, const float* __restrict__ b2,
    float* __restrict__ out, int G)
{
    const int g0 = blockIdx.x * 4;
    __shared__ float p[4][HC];
    const int t = threadIdx.x;
    for (int i = t; i < 4 * HC; i += 256) {
        const int gg = g0 + (i >> 7);
        p[i >> 7][i & 127] = (gg < G) ? pooled[(size_t)gg * HC + (i & 127)] : 0.f;
    }
    __syncthreads();
    for (int j = t; j < NOUT; j += 256) {
        const float bj = b2[j];
        float a0 = bj, a1 = bj, a2 = bj, a3 = bj;
        #pragma unroll 4
        for (int c = 0; c < HC; ++c) {
            const float w = W2[(size_t)c * NOUT + j];
            a0 = fmaf(p[0][c], w, a0);
            a1 = fmaf(p[1][c], w, a1);
            a2 = fmaf(p[2][c], w, a2);
            a3 = fmaf(p[3][c], w, a3);
        }
        if (g0     < G) out[(size_t)(g0    ) * NOUT + j] = a0;
        if (g0 + 1 < G) out[(size_t)(g0 + 1) * NOUT + j] = a1;
        if (g0 + 2 < G) out[(size_t)(g0 + 2) * NOUT + j] = a2;
        if (g0 + 3 < G) out[(size_t)(g0 + 3) * NOUT + j] = a3;
    }
}

// ---------------- launch ----------------
extern "C" void kernel_launch(void* const* d_in, const int* in_sizes, int n_in,
                              void* d_out, int out_size, void* d_ws, size_t ws_size,
                              hipStream_t stream) {
    const float* x     = (const float*)d_in[0];
    const int*   ei    = (const int*)d_in[1];
    const int*   batch = (const int*)d_in[2];
    const float* Wq  = (const float*)d_in[3];  const float* bq  = (const float*)d_in[4];
    const float* Wk  = (const float*)d_in[5];  const float* bk  = (const float*)d_in[6];
    const float* Wv  = (const float*)d_in[7];  const float* bv  = (const float*)d_in[8];
    const float* Wsk = (const float*)d_in[9];  const float* bsk = (const float*)d_in[10];
    const float* Wbeta = (const float*)d_in[11];
    const float* W2  = (const float*)d_in[12]; const float* b2  = (const float*)d_in[13];

    const int N = in_sizes[0] / NIN;
    const int E = in_sizes[1] / 2;
    const int G = out_size / NOUT;

    char* ws = (char*)d_ws;
    const size_t nbQ = (size_t)N * HC * sizeof(__hip_bfloat16);
    __hip_bfloat16* q    = (__hip_bfloat16*)(ws);
    __hip_bfloat16* kk_  = (__hip_bfloat16*)(ws + nbQ);
    __hip_bfloat16* vv   = (__hip_bfloat16*)(ws + 2 * nbQ);
    __hip_bfloat16* skip = (__hip_bfloat16*)(ws + 3 * nbQ);
    char* p0 = ws + 4 * nbQ;
    unsigned short* Wtb = (unsigned short*)p0;            p0 += 4 * 128 * 128 * sizeof(unsigned short);
    int* cnt    = (int*)p0;                               p0 += (size_t)N * sizeof(int);
    int* start  = (int*)p0;                               p0 += (size_t)N * sizeof(int);
    int* cursor = (int*)p0;                               p0 += (size_t)N * sizeof(int);
    int* bsum   = (int*)p0;                               p0 += 1024 * sizeof(int);
    int* csr    = (int*)p0;                               p0 += (size_t)E * sizeof(int);
    __hip_bfloat16* gout = (__hip_bfloat16*)p0;           p0 += nbQ;
    float* pooled = (float*)p0;

    hipMemsetAsync(cnt, 0, (size_t)N * sizeof(int), stream);

    const int eb = (E + 255) / 256;
    const int NB = (N + 1023) / 1024;
    hist_kernel<<<eb, 256, 0, stream>>>(ei, cnt, E);
    scan_part<<<NB, 1024, 0, stream>>>(cnt, start, bsum, N);
    scan_bsum<<<1, 128, 0, stream>>>(bsum, NB);
    scan_add<<<(N + 255) / 256, 256, 0, stream>>>(start, cursor, bsum, N);
    scatter_kernel<<<eb, 256, 0, stream>>>(ei, cursor, csr, E);

    prep_w<<<4, 256, 0, stream>>>(Wq, Wk, Wv, Wsk, Wtb);
    gemm4_mfma<<<(N + 63) / 64, 256, 0, stream>>>(x, Wtb, bq, bk, bv, bsk, q, N);

    node_aggr<<<(N + 3) / 4, 256, 0, stream>>>(q, kk_, vv, skip, start, cnt, csr,
                                               Wbeta, gout, N);

    pool_graph<<<G, 128, 0, stream>>>(gout, batch, pooled, N);
    final_gemm<<<(G + 3) / 4, 256, 0, stream>>>(pooled, W2, b2, (float*)d_out, G);
}

// Round 8
// 360.042 us; speedup vs baseline: 1.1326x; 1.1326x over previous
//
#include <hip/hip_runtime.h>
#include <hip/hip_bf16.h>
#include <math.h>

#define NIN 128
#define HC 128
#define NOUT 768

typedef __attribute__((ext_vector_type(8))) short bf16x8;
typedef __attribute__((ext_vector_type(4))) float f32x4;
typedef __attribute__((ext_vector_type(4))) unsigned short ushort4v;
typedef __attribute__((ext_vector_type(8))) unsigned short ushort8v;

__device__ __forceinline__ unsigned short f2bf(float f) {
    __hip_bfloat16 h = __float2bfloat16(f);
    return *(unsigned short*)&h;
}

// ---------------- prep: W[k][n] fp32 -> Wt[n][k] bf16 (4 weights) ----------------
__global__ __launch_bounds__(256) void prep_w(
    const float* __restrict__ Wq, const float* __restrict__ Wk,
    const float* __restrict__ Wv, const float* __restrict__ Wsk,
    unsigned short* __restrict__ Wtb)
{
    const float* W = (blockIdx.x == 0) ? Wq : (blockIdx.x == 1) ? Wk
                   : (blockIdx.x == 2) ? Wv : Wsk;
    unsigned short* out = Wtb + (size_t)blockIdx.x * 128 * 128;
    const int t = threadIdx.x;
    for (int s = 0; s < 16; ++s) {
        const int f = t + s * 256;           // float4 index (4096 total)
        const int k = f >> 5;
        const int n = (f & 31) * 4;
        float4 w4 = *(const float4*)(W + (size_t)k * 128 + n);
        out[(size_t)(n    ) * 128 + k] = f2bf(w4.x);
        out[(size_t)(n + 1) * 128 + k] = f2bf(w4.y);
        out[(size_t)(n + 2) * 128 + k] = f2bf(w4.z);
        out[(size_t)(n + 3) * 128 + k] = f2bf(w4.w);
    }
}

// ---------------- Kernel A: MFMA projections for k,v only (R5 structure) ----------------
__global__ __launch_bounds__(256, 4) void gemm_kv(
    const float* __restrict__ x, const unsigned short* __restrict__ Wtb,
    const float* __restrict__ bk, const float* __restrict__ bv,
    __hip_bfloat16* __restrict__ kout, __hip_bfloat16* __restrict__ vout, int N)
{
    __shared__ unsigned short At[128][136];
    const int tid = threadIdx.x;
    const int lane = tid & 63;
    const int wave = tid >> 6;
    const int rowBase = blockIdx.x * 128;
    const bool full = (rowBase + 128 <= N);

    // stage x fp32 -> bf16 LDS
    #pragma unroll
    for (int s = 0; s < 16; ++s) {
        const int f = tid + s * 256;          // float4 idx
        const int r = f >> 5;
        const int cl = (f & 31) * 4;
        const int gr = rowBase + r;
        float4 a4 = make_float4(0.f, 0.f, 0.f, 0.f);
        if (full || gr < N) a4 = *(const float4*)(x + (size_t)gr * 128 + cl);
        ushort4v u;
        u.x = f2bf(a4.x); u.y = f2bf(a4.y); u.z = f2bf(a4.z); u.w = f2bf(a4.w);
        *(ushort4v*)&At[r][cl] = u;
    }
    __syncthreads();

    bf16x8 afr[2][4];
    #pragma unroll
    for (int m = 0; m < 2; ++m)
        #pragma unroll
        for (int kk = 0; kk < 4; ++kk)
            afr[m][kk] = *(bf16x8*)&At[wave * 32 + m * 16 + (lane & 15)]
                                    [kk * 32 + (lane >> 4) * 8];

    const int colb = lane & 15;
    const int kofs = (lane >> 4) * 8;
    const int g4   = (lane >> 4) * 4;

    #pragma unroll
    for (int w2 = 0; w2 < 2; ++w2) {
        const unsigned short* Wp = Wtb + (size_t)(1 + w2) * 128 * 128;  // Wk, Wv
        const float* bias = (w2 == 0) ? bk : bv;
        __hip_bfloat16* out = (w2 == 0) ? kout : vout;

        f32x4 acc[2][8];
        #pragma unroll
        for (int m = 0; m < 2; ++m)
            #pragma unroll
            for (int nr = 0; nr < 8; ++nr)
                acc[m][nr] = (f32x4){0.f, 0.f, 0.f, 0.f};

        #pragma unroll
        for (int nr = 0; nr < 8; ++nr) {
            bf16x8 bfr[4];
            #pragma unroll
            for (int kk = 0; kk < 4; ++kk)
                bfr[kk] = *(const bf16x8*)(Wp + (size_t)(nr * 16 + colb) * 128
                                               + kk * 32 + kofs);
            #pragma unroll
            for (int kk = 0; kk < 4; ++kk) {
                #pragma unroll
                for (int m = 0; m < 2; ++m)
                    acc[m][nr] = __builtin_amdgcn_mfma_f32_16x16x32_bf16(
                        bfr[kk], afr[m][kk], acc[m][nr], 0, 0, 0);   // swapped
            }
        }

        #pragma unroll
        for (int m = 0; m < 2; ++m) {
            const int xrow = rowBase + wave * 32 + m * 16 + (lane & 15);
            if (full || xrow < N) {
                #pragma unroll
                for (int nr = 0; nr < 8; ++nr) {
                    const int colb4 = nr * 16 + g4;
                    const float4 b4 = *(const float4*)(bias + colb4);
                    ushort4v pk;
                    pk.x = f2bf(acc[m][nr][0] + b4.x);
                    pk.y = f2bf(acc[m][nr][1] + b4.y);
                    pk.z = f2bf(acc[m][nr][2] + b4.z);
                    pk.w = f2bf(acc[m][nr][3] + b4.w);
                    *(ushort4v*)(out + (size_t)xrow * 128 + colb4) = pk;
                }
            }
        }
    }
}

// ---------------- CSR build ----------------
__global__ __launch_bounds__(256) void hist_kernel(
    const int* __restrict__ ei, int* __restrict__ cnt, int E)
{
    const int e = blockIdx.x * 256 + threadIdx.x;
    if (e < E) atomicAdd(cnt + ei[E + e], 1);
}

__global__ __launch_bounds__(1024) void scan_part(
    const int* __restrict__ cnt, int* __restrict__ start,
    int* __restrict__ bsum, int N)
{
    __shared__ int wsum[16];
    const int tid = threadIdx.x;
    const int lane = tid & 63;
    const int w = tid >> 6;
    const int i = blockIdx.x * 1024 + tid;
    const int v = (i < N) ? cnt[i] : 0;
    int xv = v;
    #pragma unroll
    for (int off = 1; off < 64; off <<= 1) {
        const int y = __shfl_up(xv, off, 64);
        if (lane >= off) xv += y;
    }
    if (lane == 63) wsum[w] = xv;
    __syncthreads();
    if (tid < 16) {
        int y = wsum[tid];
        #pragma unroll
        for (int off = 1; off < 16; off <<= 1) {
            const int z = __shfl_up(y, off, 64);
            if (tid >= off) y += z;
        }
        wsum[tid] = y;
    }
    __syncthreads();
    const int excl = (w > 0 ? wsum[w - 1] : 0) + xv - v;
    if (i < N) start[i] = excl;
    if (tid == 1023) bsum[blockIdx.x] = wsum[15];
}

__global__ __launch_bounds__(128) void scan_bsum(int* __restrict__ bsum, int NB)
{
    const int tid = threadIdx.x;
    __shared__ int w0tot;
    const int v = (tid < NB) ? bsum[tid] : 0;
    int xv = v;
    const int lane = tid & 63;
    #pragma unroll
    for (int off = 1; off < 64; off <<= 1) {
        const int y = __shfl_up(xv, off, 64);
        if (lane >= off) xv += y;
    }
    if (tid == 63) w0tot = xv;
    __syncthreads();
    const int incl = xv + ((tid >= 64) ? w0tot : 0);
    if (tid < NB) bsum[tid] = incl - v;     // exclusive
}

__global__ __launch_bounds__(256) void scan_add(
    int* __restrict__ start, int* __restrict__ cursor,
    const int* __restrict__ bsum, int N)
{
    const int i = blockIdx.x * 256 + threadIdx.x;
    if (i < N) {
        const int s = start[i] + bsum[i >> 10];
        start[i] = s;
        cursor[i] = s;
    }
}

__global__ __launch_bounds__(256) void scatter_kernel(
    const int* __restrict__ ei, int* __restrict__ cursor,
    int* __restrict__ csr_src, int E)
{
    const int e = blockIdx.x * 256 + threadIdx.x;
    if (e < E) {
        const int d = ei[E + e];
        const int pos = atomicAdd(cursor + d, 1);
        csr_src[pos] = ei[e];
    }
}

// ---------------- Kernel B: fused q/skip-MFMA + attention + gate ----------------
// Block = 16 nodes, 4 waves. Phase 1: stage x rows, MFMA q & skip into LDS (fp32).
// Phase 2: wave w handles nodes 4w..4w+3 (CSR gather of k,v; src idx preloaded
// 64-wide and distributed by shfl).
__global__ __launch_bounds__(256) void node_aggr_fused(
    const float* __restrict__ x, const unsigned short* __restrict__ Wtb,
    const float* __restrict__ bq, const float* __restrict__ bsk,
    const __hip_bfloat16* __restrict__ k, const __hip_bfloat16* __restrict__ v,
    const int* __restrict__ start, const int* __restrict__ cnt,
    const int* __restrict__ csr_src, const float* __restrict__ Wbeta,
    __hip_bfloat16* __restrict__ gout, int N)
{
    __shared__ unsigned short At[16][136];
    __shared__ float q_lds[16][132];
    __shared__ float sk_lds[16][132];

    const int tid = threadIdx.x;
    const int lane = tid & 63;
    const int wave = tid >> 6;
    const int n0 = blockIdx.x * 16;

    // stage x rows n0..n0+15 -> bf16 LDS
    #pragma unroll
    for (int s = 0; s < 2; ++s) {
        const int f = tid + s * 256;          // float4 idx (512 total)
        const int r = f >> 5;
        const int cl = (f & 31) * 4;
        const int gr = n0 + r;
        float4 a4 = make_float4(0.f, 0.f, 0.f, 0.f);
        if (gr < N) a4 = *(const float4*)(x + (size_t)gr * 128 + cl);
        ushort4v u;
        u.x = f2bf(a4.x); u.y = f2bf(a4.y); u.z = f2bf(a4.z); u.w = f2bf(a4.w);
        *(ushort4v*)&At[r][cl] = u;
    }
    __syncthreads();

    // MFMA q & skip for these 16 rows; wave w computes out-cols [w*32, w*32+32)
    {
        bf16x8 afr[4];
        #pragma unroll
        for (int kk = 0; kk < 4; ++kk)
            afr[kk] = *(bf16x8*)&At[lane & 15][kk * 32 + (lane >> 4) * 8];
        const int colb = lane & 15;
        const int kofs = (lane >> 4) * 8;
        const int g4   = (lane >> 4) * 4;
        const int r    = lane & 15;

        f32x4 acc[2][2];   // [q/skip][nr2]
        #pragma unroll
        for (int a = 0; a < 2; ++a)
            #pragma unroll
            for (int b = 0; b < 2; ++b)
                acc[a][b] = (f32x4){0.f, 0.f, 0.f, 0.f};

        #pragma unroll
        for (int nr2 = 0; nr2 < 2; ++nr2) {
            const int nr = wave * 2 + nr2;
            #pragma unroll
            for (int wsel = 0; wsel < 2; ++wsel) {
                const unsigned short* Wp = Wtb + (size_t)(wsel == 0 ? 0 : 3) * 128 * 128;
                bf16x8 bfr[4];
                #pragma unroll
                for (int kk = 0; kk < 4; ++kk)
                    bfr[kk] = *(const bf16x8*)(Wp + (size_t)(nr * 16 + colb) * 128
                                                   + kk * 32 + kofs);
                #pragma unroll
                for (int kk = 0; kk < 4; ++kk)
                    acc[wsel][nr2] = __builtin_amdgcn_mfma_f32_16x16x32_bf16(
                        bfr[kk], afr[kk], acc[wsel][nr2], 0, 0, 0);
            }
        }

        #pragma unroll
        for (int nr2 = 0; nr2 < 2; ++nr2) {
            const int col = (wave * 2 + nr2) * 16 + g4;
            #pragma unroll
            for (int j = 0; j < 4; ++j) {
                q_lds[r][col + j]  = acc[0][nr2][j] + bq[col + j];
                sk_lds[r][col + j] = acc[1][nr2][j] + bsk[col + j];
            }
        }
    }
    __syncthreads();

    // attention + gate: wave handles 4 nodes
    const int c = 2 * lane;
    const float scale = 0.17677669529663687f;   // 1/sqrt(32)
    const float wb0 = Wbeta[c],          wb1 = Wbeta[c + 1];
    const float wb2 = Wbeta[HC + c],     wb3 = Wbeta[HC + c + 1];
    const float wb4 = Wbeta[2 * HC + c], wb5 = Wbeta[2 * HC + c + 1];

    for (int rr = 0; rr < 4; ++rr) {
        const int r = wave * 4 + rr;
        const int n = n0 + r;
        if (n >= N) break;
        const float qx = q_lds[r][c], qy = q_lds[r][c + 1];

        const int s0 = start[n];
        const int e1 = s0 + cnt[n];
        float den = 0.f, a0 = 0.f, a1 = 0.f;
        for (int cb = s0; cb < e1; cb += 64) {
            const int len = min(64, e1 - cb);
            const int my = cb + lane;
            int sidx = (my < e1) ? csr_src[my] : 0;
            int j = 0;
            for (; j + 1 < len; j += 2) {
                const int sa = __shfl(sidx, j, 64);
                const int sb = __shfl(sidx, j + 1, 64);
                const __hip_bfloat162 k2a = *(const __hip_bfloat162*)(k + (size_t)sa * HC + c);
                const __hip_bfloat162 v2a = *(const __hip_bfloat162*)(v + (size_t)sa * HC + c);
                const __hip_bfloat162 k2b = *(const __hip_bfloat162*)(k + (size_t)sb * HC + c);
                const __hip_bfloat162 v2b = *(const __hip_bfloat162*)(v + (size_t)sb * HC + c);
                float pa = qx * __bfloat162float(k2a.x) + qy * __bfloat162float(k2a.y);
                float pb = qx * __bfloat162float(k2b.x) + qy * __bfloat162float(k2b.y);
                #pragma unroll
                for (int m = 1; m < 16; m <<= 1) {
                    pa += __shfl_xor(pa, m, 64);
                    pb += __shfl_xor(pb, m, 64);
                }
                const float exa = __expf(pa * scale);
                const float exb = __expf(pb * scale);
                den += exa + exb;
                a0 = fmaf(__bfloat162float(v2a.x), exa, fmaf(__bfloat162float(v2b.x), exb, a0));
                a1 = fmaf(__bfloat162float(v2a.y), exa, fmaf(__bfloat162float(v2b.y), exb, a1));
            }
            if (j < len) {
                const int sa = __shfl(sidx, j, 64);
                const __hip_bfloat162 k2a = *(const __hip_bfloat162*)(k + (size_t)sa * HC + c);
                const __hip_bfloat162 v2a = *(const __hip_bfloat162*)(v + (size_t)sa * HC + c);
                float pa = qx * __bfloat162float(k2a.x) + qy * __bfloat162float(k2a.y);
                #pragma unroll
                for (int m = 1; m < 16; m <<= 1) pa += __shfl_xor(pa, m, 64);
                const float exa = __expf(pa * scale);
                den += exa;
                a0 = fmaf(__bfloat162float(v2a.x), exa, a0);
                a1 = fmaf(__bfloat162float(v2a.y), exa, a1);
            }
        }

        const float inv = 1.f / (den + 1e-16f);
        const float o0 = a0 * inv, o1 = a1 * inv;
        const float sk0 = sk_lds[r][c], sk1 = sk_lds[r][c + 1];

        float part = o0 * wb0 + o1 * wb1 + sk0 * wb2 + sk1 * wb3
                   + (o0 - sk0) * wb4 + (o1 - sk1) * wb5;
        #pragma unroll
        for (int m = 1; m < 64; m <<= 1) part += __shfl_xor(part, m, 64);

        const float beta = 1.f / (1.f + __expf(-part));
        float r0 = beta * sk0 + (1.f - beta) * o0;
        float r1 = beta * sk1 + (1.f - beta) * o1;
        r0 = (r0 >= 0.f) ? r0 : 0.01f * r0;
        r1 = (r1 >= 0.f) ? r1 : 0.01f * r1;

        __hip_bfloat162 g2;
        g2.x = __float2bfloat16(r0);
        g2.y = __float2bfloat16(r1);
        *(__hip_bfloat162*)(gout + (size_t)n * HC + c) = g2;
    }
}

// ---------------- pool per graph (batch sorted; binary search the range) ----------------
__global__ __launch_bounds__(128) void pool_graph(
    const __hip_bfloat16* __restrict__ gout, const int* __restrict__ batch,
    float* __restrict__ pooled, int N)
{
    const int g = blockIdx.x;
    const int t = threadIdx.x;
    int lo = 0, hi = N;
    while (lo < hi) { const int m = (lo + hi) >> 1; if (batch[m] < g) lo = m + 1; else hi = m; }
    int lo2 = lo, hi2 = N;
    while (lo2 < hi2) { const int m = (lo2 + hi2) >> 1; if (batch[m] < g + 1) lo2 = m + 1; else hi2 = m; }
    float acc = 0.f;
    for (int r = lo; r < lo2; ++r)
        acc += __bfloat162float(gout[(size_t)r * HC + t]);
    pooled[(size_t)g * HC + t] = acc / fmaxf((float)(lo2 - lo), 1.f);
}

// ---------------- final GEMM: 4 graphs per block (W2 reuse x4) ----------------
__global__ __launch_bounds__(256) void final_gemm(
    const float* __restrict__ pooled,
    const float* __restrict__ W2, const float* __restrict__ b2,
    float* __restrict__ out, int G)
{
    const int g0 = blockIdx.x * 4;
    __shared__ float p[4][HC];
    const int t = threadIdx.x;
    for (int i = t; i < 4 * HC; i += 256) {
        const int gg = g0 + (i >> 7);
        p[i >> 7][i & 127] = (gg < G) ? pooled[(size_t)gg * HC + (i & 127)] : 0.f;
    }
    __syncthreads();
    for (int j = t; j < NOUT; j += 256) {
        const float bj = b2[j];
        float a0 = bj, a1 = bj, a2 = bj, a3 = bj;
        #pragma unroll 4
        for (int c = 0; c < HC; ++c) {
            const float w = W2[(size_t)c * NOUT + j];
            a0 = fmaf(p[0][c], w, a0);
            a1 = fmaf(p[1][c], w, a1);
            a2 = fmaf(p[2][c], w, a2);
            a3 = fmaf(p[3][c], w, a3);
        }
        if (g0     < G) out[(size_t)(g0    ) * NOUT + j] = a0;
        if (g0 + 1 < G) out[(size_t)(g0 + 1) * NOUT + j] = a1;
        if (g0 + 2 < G) out[(size_t)(g0 + 2) * NOUT + j] = a2;
        if (g0 + 3 < G) out[(size_t)(g0 + 3) * NOUT + j] = a3;
    }
}

// ---------------- launch ----------------
extern "C" void kernel_launch(void* const* d_in, const int* in_sizes, int n_in,
                              void* d_out, int out_size, void* d_ws, size_t ws_size,
                              hipStream_t stream) {
    const float* x     = (const float*)d_in[0];
    const int*   ei    = (const int*)d_in[1];
    const int*   batch = (const int*)d_in[2];
    const float* Wq  = (const float*)d_in[3];  const float* bq  = (const float*)d_in[4];
    const float* Wk  = (const float*)d_in[5];  const float* bk  = (const float*)d_in[6];
    const float* Wv  = (const float*)d_in[7];  const float* bv  = (const float*)d_in[8];
    const float* Wsk = (const float*)d_in[9];  const float* bsk = (const float*)d_in[10];
    const float* Wbeta = (const float*)d_in[11];
    const float* W2  = (const float*)d_in[12]; const float* b2  = (const float*)d_in[13];

    const int N = in_sizes[0] / NIN;
    const int E = in_sizes[1] / 2;
    const int G = out_size / NOUT;

    char* ws = (char*)d_ws;
    const size_t nbQ = (size_t)N * HC * sizeof(__hip_bfloat16);
    __hip_bfloat16* kk_  = (__hip_bfloat16*)(ws);
    __hip_bfloat16* vv   = (__hip_bfloat16*)(ws + nbQ);
    char* p0 = ws + 2 * nbQ;
    unsigned short* Wtb = (unsigned short*)p0;            p0 += 4 * 128 * 128 * sizeof(unsigned short);
    int* cnt    = (int*)p0;                               p0 += (size_t)N * sizeof(int);
    int* start  = (int*)p0;                               p0 += (size_t)N * sizeof(int);
    int* cursor = (int*)p0;                               p0 += (size_t)N * sizeof(int);
    int* bsum   = (int*)p0;                               p0 += 1024 * sizeof(int);
    int* csr    = (int*)p0;                               p0 += (size_t)E * sizeof(int);
    __hip_bfloat16* gout = (__hip_bfloat16*)p0;           p0 += nbQ;
    float* pooled = (float*)p0;

    hipMemsetAsync(cnt, 0, (size_t)N * sizeof(int), stream);

    const int eb = (E + 255) / 256;
    const int NB = (N + 1023) / 1024;
    hist_kernel<<<eb, 256, 0, stream>>>(ei, cnt, E);
    scan_part<<<NB, 1024, 0, stream>>>(cnt, start, bsum, N);
    scan_bsum<<<1, 128, 0, stream>>>(bsum, NB);
    scan_add<<<(N + 255) / 256, 256, 0, stream>>>(start, cursor, bsum, N);
    scatter_kernel<<<eb, 256, 0, stream>>>(ei, cursor, csr, E);

    prep_w<<<4, 256, 0, stream>>>(Wq, Wk, Wv, Wsk, Wtb);
    gemm_kv<<<(N + 127) / 128, 256, 0, stream>>>(x, Wtb, bk, bv, kk_, vv, N);

    node_aggr_fused<<<(N + 15) / 16, 256, 0, stream>>>(x, Wtb, bq, bsk, kk_, vv,
                                                       start, cnt, csr, Wbeta,
                                                       gout, N);

    pool_graph<<<G, 128, 0, stream>>>(gout, batch, pooled, N);
    final_gemm<<<(G + 3) / 4, 256, 0, stream>>>(pooled, W2, b2, (float*)d_out, G);
}